// Round 1
// baseline (43134.286 us; speedup 1.0000x reference)
//
#include <hip/hip_runtime.h>
#include <math.h>

#define Tt 512
#define Dd 768
#define Hh 512
#define Bb 32
#define G3 1536
#define HB (Hh*Bb)
#define NBLK 256
#define NBAR (Tt*4)

__device__ __forceinline__ float sigf(float x) { return 1.f / (1.f + expf(-x)); }

__device__ __forceinline__ float dot4f(const float4 w4, const float* v) {
  return w4.x*v[0] + w4.y*v[1] + w4.z*v[2] + w4.w*v[3];
}

// ---------------- grid barrier (device-scope, monotone counters) ----------------
__device__ __forceinline__ void grid_barrier(unsigned* c1, unsigned* c2, unsigned* fl, int idx)
{
  __syncthreads();
  if (threadIdx.x == 0) {
    __builtin_amdgcn_fence(__ATOMIC_RELEASE, "agent");      // write back dirty L2
    unsigned grp = (unsigned)(blockIdx.x >> 4);             // 16 groups of 16 blocks
    unsigned old = __hip_atomic_fetch_add(&c1[((size_t)idx*16u + grp) * 16u], 1u,
                        __ATOMIC_RELAXED, __HIP_MEMORY_SCOPE_AGENT);
    if (old == 15u) {
      unsigned o2 = __hip_atomic_fetch_add(&c2[idx], 1u,
                        __ATOMIC_RELAXED, __HIP_MEMORY_SCOPE_AGENT);
      if (o2 == 15u)
        __hip_atomic_store(fl, (unsigned)(idx + 1), __ATOMIC_RELAXED, __HIP_MEMORY_SCOPE_AGENT);
    }
    while (__hip_atomic_load(fl, __ATOMIC_RELAXED, __HIP_MEMORY_SCOPE_AGENT) < (unsigned)(idx + 1))
      __builtin_amdgcn_s_sleep(1);
    __builtin_amdgcn_fence(__ATOMIC_ACQUIRE, "agent");      // invalidate L1/L2
  }
  __syncthreads();
}

// ---------------- GI0 = x @ Wih0^T + bih0, layout [t][j][b] ----------------
__global__ __launch_bounds__(256) void gi0_gemm(const float* __restrict__ x,
                                                const float* __restrict__ Wih0,
                                                const float* __restrict__ bih0,
                                                float* __restrict__ GI0)
{
  const int t  = blockIdx.x;          // 0..511
  const int j0 = blockIdx.y * 128;    // 0..11 tiles of 128
  const int tid = threadIdx.x;
  const int b = tid & 31, u = tid >> 5;

  __shared__ float xs[128][33];       // [k][b] padded
  float acc[16];
#pragma unroll
  for (int jj = 0; jj < 16; jj++) acc[jj] = 0.f;

  for (int kbv = 0; kbv < Dd; kbv += 128) {
    __syncthreads();
    {
      int bb = tid >> 3, kg = (tid & 7) * 4;
      const float* xp = x + ((size_t)bb * Tt + t) * Dd + kbv;
#pragma unroll
      for (int q = 0; q < 4; q++) {
        float4 v = *(const float4*)(xp + kg + q * 32);
        int k = kg + q * 32;
        xs[k + 0][bb] = v.x; xs[k + 1][bb] = v.y;
        xs[k + 2][bb] = v.z; xs[k + 3][bb] = v.w;
      }
    }
    __syncthreads();
    for (int kk = 0; kk < 128; kk += 4) {
      float x0 = xs[kk][b], x1 = xs[kk + 1][b], x2 = xs[kk + 2][b], x3 = xs[kk + 3][b];
#pragma unroll
      for (int jj = 0; jj < 16; jj++) {
        const float* wp = Wih0 + (size_t)(j0 + u + 8 * jj) * Dd + kbv + kk;
        float4 w4 = *(const float4*)wp;
        acc[jj] += w4.x * x0 + w4.y * x1 + w4.z * x2 + w4.w * x3;
      }
    }
  }
#pragma unroll
  for (int jj = 0; jj < 16; jj++) {
    int j = j0 + u + 8 * jj;
    GI0[((size_t)t * G3 + j) * 32 + b] = acc[jj] + bih0[j];
  }
}

// ---------------- persistent HRNN kernel ----------------
__global__ __launch_bounds__(256, 1) void hrnn_persist(
    const float* __restrict__ Whh0, const float* __restrict__ bhh0,
    const float* __restrict__ Wih,  const float* __restrict__ Whh,
    const float* __restrict__ bih,  const float* __restrict__ bhh,
    const float* __restrict__ mW1,  const float* __restrict__ mb1,
    const float* __restrict__ mW2,  const float* __restrict__ mb2,
    const float* __restrict__ mW3,  const float* __restrict__ mb3,
    const float* __restrict__ GI0,
    float* __restrict__ c0T, float* __restrict__ c1T, float* __restrict__ c2T,
    float* __restrict__ m0aT, float* __restrict__ m0bT,
    float* __restrict__ m1aT, float* __restrict__ m1bT,
    unsigned* __restrict__ bc1, unsigned* __restrict__ bc2, unsigned* __restrict__ bfl,
    float* __restrict__ out)
{
  __shared__ float red[8][576];
  __shared__ float s_gh[12][32];   // gh for layers 1,2 (bias included)
  __shared__ float s_pre[6][32];   // layer0: g<2 full preact; g=2 gh_n only
  __shared__ float s_gi[6][32];
  __shared__ float s_ab[7][32];    // a0,a1,a2,b0,b1,p0,p1

  const int tid = threadIdx.x;
  const int b = tid & 31;
  const int u = tid >> 5;
  const int i0 = blockIdx.x * 2;   // this block's 2 columns of H
  const int kb = u * 64;
  int baridx = 0;

  for (int t = 0; t < Tt; t++) {
    const int par = t & 1;
    const float* c0o = c0T + (size_t)(1 - par) * HB;
    float* c0n = c0T + (size_t)par * HB;

    // ---- p-phase: recompute p0(t-1), p1(t-1) and mixing weights ----
    {
      float s0 = 0.f, s1 = 0.f;
      for (int kk = 0; kk < 64; kk++) {
        int k = kb + kk;
        s0 += mW3[k]       * m0bT[k * 32 + b];
        s1 += mW3[512 + k] * m1bT[k * 32 + b];
      }
      red[u][b] = s0; red[u][32 + b] = s1;
      __syncthreads();
      if (tid < 64) {
        float s = 0.f;
#pragma unroll
        for (int uu = 0; uu < 8; uu++) s += red[uu][tid];
        int which = tid >> 5, bb = tid & 31;
        s_ab[5 + which][bb] = sigf(s + mb3[which]);
      }
      __syncthreads();
      if (tid < 32) {
        float p0 = s_ab[5][tid], p1 = s_ab[6][tid];
        float e0 = expf(1.f - p0), e1 = expf(p0 * (1.f - p1)), e2 = expf(p0 * p1);
        float inv = 1.f / (e0 + e1 + e2);
        s_ab[0][tid] = e0 * inv; s_ab[1][tid] = e1 * inv; s_ab[2][tid] = e2 * inv;
        float q0 = expf(1.f - p1), q1 = expf(p1);
        float qi = 1.f / (q0 + q1);
        s_ab[3][tid] = q0 * qi; s_ab[4][tid] = q1 * qi;
        if (t > 0 && blockIdx.x == 0) {
          out[((size_t)tid * Tt + (t - 1)) * 2 + 0] = p0;
          out[((size_t)tid * Tt + (t - 1)) * 2 + 1] = p1;
        }
      }
      __syncthreads();
    }

    const float a0 = s_ab[0][b], a1 = s_ab[1][b], a2 = s_ab[2][b];
    const float w10 = s_ab[3][b], w11 = s_ab[4][b];

    // ---- S1: gh0/gh1/gh2 with inline h-mixing; cell0 ----
    {
      float acc[18];
#pragma unroll
      for (int w = 0; w < 18; w++) acc[w] = 0.f;
      for (int kk = 0; kk < 64; kk += 4) {
        float mh0[4], mh1[4], vv2[4];
#pragma unroll
        for (int q = 0; q < 4; q++) {
          int k = kb + kk + q;
          float v0 = c0o[k * 32 + b], v1 = c1T[k * 32 + b], v2 = c2T[k * 32 + b];
          vv2[q] = v2;
          mh0[q] = a0 * v0 + a1 * v1 + a2 * v2;
          mh1[q] = w10 * v1 + w11 * v2;
        }
#pragma unroll
        for (int w = 0; w < 18; w++) {
          const int l = w / 6, rem = w % 6, g = rem >> 1, ii = rem & 1;
          const int row = g * 512 + i0 + ii;
          const float* wp = (l == 0) ? (Whh0 + (size_t)row * 512)
                                     : (Whh + ((size_t)(l - 1) * G3 + row) * 512);
          float4 w4 = *(const float4*)(wp + kb + kk);
          const float* mv = (l == 0) ? mh0 : (l == 1) ? mh1 : vv2;
          acc[w] += dot4f(w4, mv);
        }
      }
#pragma unroll
      for (int w = 0; w < 18; w++) red[u][w * 32 + b] = acc[w];
      __syncthreads();
      for (int o = tid; o < 18 * 32; o += 256) {
        float s = 0.f;
#pragma unroll
        for (int uu = 0; uu < 8; uu++) s += red[uu][o];
        int w = o >> 5, b2 = o & 31;
        int l = w / 6, rem = w % 6, g = rem >> 1, ii = rem & 1;
        int row = g * 512 + i0 + ii;
        if (l == 0) {
          s += bhh0[row];
          if (g < 2) s += GI0[((size_t)t * G3 + row) * 32 + b2];
          s_pre[rem][b2] = s;
        } else if (l == 1) {
          s_gh[rem][b2] = s + bhh[row];
        } else {
          s_gh[6 + rem][b2] = s + bhh[G3 + row];
        }
      }
      __syncthreads();
      if (tid < 64) {
        int ii = tid >> 5, bb = tid & 31;
        float r = sigf(s_pre[ii][bb]);
        float z = sigf(s_pre[2 + ii][bb]);
        float inn = GI0[((size_t)t * G3 + 1024 + i0 + ii) * 32 + bb];
        float n = tanhf(inn + r * s_pre[4 + ii][bb]);
        int idx = (i0 + ii) * 32 + bb;
        float v0 = c0o[idx], v1 = c1T[idx], v2 = c2T[idx];
        float h0old = s_ab[0][bb] * v0 + s_ab[1][bb] * v1 + s_ab[2][bb] * v2;
        c0n[idx] = (1.f - z) * n + z * h0old;
      }
    }
    grid_barrier(bc1, bc2, bfl, baridx++);

    // ---- S2: gi1 (over cell0) + m0a; cell1 ----
    {
      float acc[8];
#pragma unroll
      for (int w = 0; w < 8; w++) acc[w] = 0.f;
      for (int kk = 0; kk < 64; kk += 4) {
        float v[4];
#pragma unroll
        for (int q = 0; q < 4; q++) v[q] = c0n[(kb + kk + q) * 32 + b];
#pragma unroll
        for (int w = 0; w < 8; w++) {
          const float* wp = (w < 6) ? (Wih + (size_t)((w >> 1) * 512 + i0 + (w & 1)) * 512)
                                    : (mW1 + (size_t)(i0 + (w - 6)) * 512);
          float4 w4 = *(const float4*)(wp + kb + kk);
          acc[w] += dot4f(w4, v);
        }
      }
#pragma unroll
      for (int w = 0; w < 8; w++) red[u][w * 32 + b] = acc[w];
      __syncthreads();
      for (int o = tid; o < 8 * 32; o += 256) {
        float s = 0.f;
#pragma unroll
        for (int uu = 0; uu < 8; uu++) s += red[uu][o];
        int w = o >> 5, b2 = o & 31;
        if (w < 6) {
          int row = (w >> 1) * 512 + i0 + (w & 1);
          s_gi[w][b2] = s + bih[row];
        } else {
          int col = i0 + (w - 6);
          m0aT[col * 32 + b2] = fmaxf(s + mb1[col], 0.f);
        }
      }
      __syncthreads();
      if (tid < 64) {
        int ii = tid >> 5, bb = tid & 31;
        float r = sigf(s_gi[ii][bb] + s_gh[ii][bb]);
        float z = sigf(s_gi[2 + ii][bb] + s_gh[2 + ii][bb]);
        float n = tanhf(s_gi[4 + ii][bb] + r * s_gh[4 + ii][bb]);
        int idx = (i0 + ii) * 32 + bb;
        float h1old = s_ab[3][bb] * c1T[idx] + s_ab[4][bb] * c2T[idx];
        c1T[idx] = (1.f - z) * n + z * h1old;
      }
    }
    grid_barrier(bc1, bc2, bfl, baridx++);

    // ---- S3: gi2 (over cell1) + m0b (over m0a) + m1a (over cell1); cell2 ----
    {
      float acc[10];
#pragma unroll
      for (int w = 0; w < 10; w++) acc[w] = 0.f;
      for (int kk = 0; kk < 64; kk += 4) {
        float v[4], vm[4];
#pragma unroll
        for (int q = 0; q < 4; q++) {
          v[q]  = c1T[(kb + kk + q) * 32 + b];
          vm[q] = m0aT[(kb + kk + q) * 32 + b];
        }
#pragma unroll
        for (int w = 0; w < 10; w++) {
          const float* wp = (w < 6) ? (Wih + (size_t)(G3 + (w >> 1) * 512 + i0 + (w & 1)) * 512)
                          : (w < 8) ? (mW2 + (size_t)(i0 + (w - 6)) * 512)
                                    : (mW1 + (size_t)(512 + i0 + (w - 8)) * 512);
          float4 w4 = *(const float4*)(wp + kb + kk);
          acc[w] += dot4f(w4, (w < 6 || w >= 8) ? v : vm);
        }
      }
#pragma unroll
      for (int w = 0; w < 10; w++) red[u][w * 32 + b] = acc[w];
      __syncthreads();
      for (int o = tid; o < 10 * 32; o += 256) {
        float s = 0.f;
#pragma unroll
        for (int uu = 0; uu < 8; uu++) s += red[uu][o];
        int w = o >> 5, b2 = o & 31;
        if (w < 6) {
          int row = (w >> 1) * 512 + i0 + (w & 1);
          s_gi[w][b2] = s + bih[G3 + row];
        } else if (w < 8) {
          int col = i0 + (w - 6);
          m0bT[col * 32 + b2] = fmaxf(s + mb2[col], 0.f);
        } else {
          int col = i0 + (w - 8);
          m1aT[col * 32 + b2] = fmaxf(s + mb1[512 + col], 0.f);
        }
      }
      __syncthreads();
      if (tid < 64) {
        int ii = tid >> 5, bb = tid & 31;
        float r = sigf(s_gi[ii][bb] + s_gh[6 + ii][bb]);
        float z = sigf(s_gi[2 + ii][bb] + s_gh[8 + ii][bb]);
        float n = tanhf(s_gi[4 + ii][bb] + r * s_gh[10 + ii][bb]);
        int idx = (i0 + ii) * 32 + bb;
        float c2old = c2T[idx];
        c2T[idx] = (1.f - z) * n + z * c2old;
      }
    }
    grid_barrier(bc1, bc2, bfl, baridx++);

    // ---- S4: m1b (over m1a) ----
    {
      float acc2[2] = {0.f, 0.f};
      for (int kk = 0; kk < 64; kk += 4) {
        float vm[4];
#pragma unroll
        for (int q = 0; q < 4; q++) vm[q] = m1aT[(kb + kk + q) * 32 + b];
#pragma unroll
        for (int w = 0; w < 2; w++) {
          const float* wp = mW2 + (size_t)(512 + i0 + w) * 512;
          float4 w4 = *(const float4*)(wp + kb + kk);
          acc2[w] += dot4f(w4, vm);
        }
      }
#pragma unroll
      for (int w = 0; w < 2; w++) red[u][w * 32 + b] = acc2[w];
      __syncthreads();
      if (tid < 64) {
        float s = 0.f;
#pragma unroll
        for (int uu = 0; uu < 8; uu++) s += red[uu][tid];
        int w = tid >> 5, b2 = tid & 31;
        int col = i0 + w;
        m1bT[col * 32 + b2] = fmaxf(s + mb2[512 + col], 0.f);
      }
    }
    grid_barrier(bc1, bc2, bfl, baridx++);
  }

  // ---- final: p(T-1) and last output column ----
  {
    float s0 = 0.f, s1 = 0.f;
    for (int kk = 0; kk < 64; kk++) {
      int k = kb + kk;
      s0 += mW3[k]       * m0bT[k * 32 + b];
      s1 += mW3[512 + k] * m1bT[k * 32 + b];
    }
    red[u][b] = s0; red[u][32 + b] = s1;
    __syncthreads();
    if (tid < 64 && blockIdx.x == 0) {
      float s = 0.f;
#pragma unroll
      for (int uu = 0; uu < 8; uu++) s += red[uu][tid];
      int which = tid >> 5, bb = tid & 31;
      out[((size_t)bb * Tt + (Tt - 1)) * 2 + which] = sigf(s + mb3[which]);
    }
  }
}

extern "C" void kernel_launch(void* const* d_in, const int* in_sizes, int n_in,
                              void* d_out, int out_size, void* d_ws, size_t ws_size,
                              hipStream_t stream)
{
  (void)in_sizes; (void)n_in; (void)out_size;
  const float* x    = (const float*)d_in[0];
  const float* Wih0 = (const float*)d_in[1];
  const float* Whh0 = (const float*)d_in[2];
  const float* bih0 = (const float*)d_in[3];
  const float* bhh0 = (const float*)d_in[4];
  const float* Wih  = (const float*)d_in[5];
  const float* Whh  = (const float*)d_in[6];
  const float* bih  = (const float*)d_in[7];
  const float* bhh  = (const float*)d_in[8];
  const float* mW1  = (const float*)d_in[9];
  const float* mb1  = (const float*)d_in[10];
  const float* mW2  = (const float*)d_in[11];
  const float* mb2  = (const float*)d_in[12];
  const float* mW3  = (const float*)d_in[13];
  const float* mb3  = (const float*)d_in[14];
  float* out = (float*)d_out;

  char* ws = (char*)d_ws;
  size_t off = 0;
  auto take = [&](size_t bytes) { size_t o = off; off = (off + bytes + 255) & ~(size_t)255; return o; };
  unsigned* bc1 = (unsigned*)(ws + take((size_t)NBAR * 16 * 16 * 4)); // padded: 1 counter per 64B
  unsigned* bc2 = (unsigned*)(ws + take((size_t)NBAR * 4));
  unsigned* bfl = (unsigned*)(ws + take(4));
  float* c0T  = (float*)(ws + take((size_t)2 * HB * 4));
  float* c1T  = (float*)(ws + take((size_t)HB * 4));
  float* c2T  = (float*)(ws + take((size_t)HB * 4));
  float* m0aT = (float*)(ws + take((size_t)HB * 4));
  float* m0bT = (float*)(ws + take((size_t)HB * 4));
  float* m1aT = (float*)(ws + take((size_t)HB * 4));
  float* m1bT = (float*)(ws + take((size_t)HB * 4));
  size_t zero_bytes = off;
  float* GI0 = (float*)(ws + take((size_t)Tt * G3 * Bb * 4));
  if (ws_size < off) return;  // workspace too small: fail visibly (no OOB writes)

  hipMemsetAsync(d_ws, 0, zero_bytes, stream);
  gi0_gemm<<<dim3(Tt, G3 / 128), 256, 0, stream>>>(x, Wih0, bih0, GI0);
  hrnn_persist<<<NBLK, 256, 0, stream>>>(Whh0, bhh0, Wih, Whh, bih, bhh,
      mW1, mb1, mW2, mb2, mW3, mb3, GI0,
      c0T, c1T, c2T, m0aT, m0bT, m1aT, m1bT, bc1, bc2, bfl, out);
}

// Round 2
// 25773.938 us; speedup vs baseline: 1.6736x; 1.6736x over previous
//
#include <hip/hip_runtime.h>
#include <math.h>

#define Tt 512
#define Dd 768
#define Hh 512
#define Bb 32
#define G3 1536
#define HB (Hh*Bb)
#define NBLK 256
#define NTHR 512
#define NBAR (Tt*4)
#define PR 32   // state ring period (staleness window; 32 steps ≈ 330MB through 4MB L2)

__device__ __forceinline__ float sigf(float x) { return 1.f / (1.f + expf(-x)); }

__device__ __forceinline__ float dot4f(const float4 w4, const float* v) {
  return w4.x*v[0] + w4.y*v[1] + w4.z*v[2] + w4.w*v[3];
}

// device-scope write-through store: lands at coherence point (MALL), no fence needed
__device__ __forceinline__ void dstore(float* p, float v) {
  __hip_atomic_store(p, v, __ATOMIC_RELAXED, __HIP_MEMORY_SCOPE_AGENT);
}

// ---------------- grid barrier: relaxed monotone atomics, no cache-nuking fences ----
// __syncthreads() emits s_waitcnt vmcnt(0) per wave => all device-scope stores of the
// block are at the coherence point before thread 0 arrives.
__device__ __forceinline__ void grid_barrier(unsigned* bc1, unsigned* bc2, unsigned* gfl, int idx)
{
  __syncthreads();
  if (threadIdx.x == 0) {
    const unsigned grp = (unsigned)(blockIdx.x >> 4);     // 16 groups x 16 blocks
    unsigned old = __hip_atomic_fetch_add(&bc1[((unsigned)idx * 16u + grp) * 16u], 1u,
                        __ATOMIC_RELAXED, __HIP_MEMORY_SCOPE_AGENT);
    if (old == 15u) {
      unsigned o2 = __hip_atomic_fetch_add(&bc2[(unsigned)idx * 16u], 1u,
                        __ATOMIC_RELAXED, __HIP_MEMORY_SCOPE_AGENT);
      if (o2 == 15u) {
#pragma unroll
        for (int g = 0; g < 16; ++g)
          __hip_atomic_store(&gfl[g * 16], (unsigned)(idx + 1),
                             __ATOMIC_RELAXED, __HIP_MEMORY_SCOPE_AGENT);
      }
    }
    while (__hip_atomic_load(&gfl[grp * 16], __ATOMIC_RELAXED, __HIP_MEMORY_SCOPE_AGENT)
           < (unsigned)(idx + 1))
      __builtin_amdgcn_s_sleep(4);
  }
  __syncthreads();
}

// ---------------- GI0 = x @ Wih0^T + bih0, layout [t][j][b] ----------------
__global__ __launch_bounds__(256) void gi0_gemm(const float* __restrict__ x,
                                                const float* __restrict__ Wih0,
                                                const float* __restrict__ bih0,
                                                float* __restrict__ GI0)
{
  const int t  = blockIdx.x;
  const int j0 = blockIdx.y * 128;
  const int tid = threadIdx.x;
  const int b = tid & 31, u = tid >> 5;

  __shared__ float xs[128][33];
  float acc[16];
#pragma unroll
  for (int jj = 0; jj < 16; jj++) acc[jj] = 0.f;

  for (int kbv = 0; kbv < Dd; kbv += 128) {
    __syncthreads();
    {
      int bb = tid >> 3, kg = (tid & 7) * 4;
      const float* xp = x + ((size_t)bb * Tt + t) * Dd + kbv;
#pragma unroll
      for (int q = 0; q < 4; q++) {
        float4 v = *(const float4*)(xp + kg + q * 32);
        int k = kg + q * 32;
        xs[k + 0][bb] = v.x; xs[k + 1][bb] = v.y;
        xs[k + 2][bb] = v.z; xs[k + 3][bb] = v.w;
      }
    }
    __syncthreads();
    for (int kk = 0; kk < 128; kk += 4) {
      float x0 = xs[kk][b], x1 = xs[kk + 1][b], x2 = xs[kk + 2][b], x3 = xs[kk + 3][b];
#pragma unroll
      for (int jj = 0; jj < 16; jj++) {
        const float* wp = Wih0 + (size_t)(j0 + u + 8 * jj) * Dd + kbv + kk;
        float4 w4 = *(const float4*)wp;
        acc[jj] += w4.x * x0 + w4.y * x1 + w4.z * x2 + w4.w * x3;
      }
    }
  }
#pragma unroll
  for (int jj = 0; jj < 16; jj++) {
    int j = j0 + u + 8 * jj;
    GI0[((size_t)t * G3 + j) * 32 + b] = acc[jj] + bih0[j];
  }
}

// ---------------- persistent HRNN kernel ----------------
__global__ __launch_bounds__(NTHR, 1) void hrnn_persist(
    const float* __restrict__ Whh0, const float* __restrict__ bhh0,
    const float* __restrict__ Wih,  const float* __restrict__ Whh,
    const float* __restrict__ bih,  const float* __restrict__ bhh,
    const float* __restrict__ mW1,  const float* __restrict__ mb1,
    const float* __restrict__ mW2,  const float* __restrict__ mb2,
    const float* __restrict__ mW3,  const float* __restrict__ mb3,
    const float* __restrict__ GI0,
    float* __restrict__ c0R, float* __restrict__ c1R, float* __restrict__ c2R,
    float* __restrict__ m0aR, float* __restrict__ m1aR,
    float* __restrict__ pacc,
    unsigned* __restrict__ bc1, unsigned* __restrict__ bc2, unsigned* __restrict__ gfl,
    float* __restrict__ out)
{
  __shared__ float red[16][576];
  __shared__ float s_gh[12][32];
  __shared__ float s_pre[6][32];
  __shared__ float s_gi[6][32];
  __shared__ float s_ab[7][32];    // a0,a1,a2,w10,w11,p0,p1
  __shared__ float s_mb[2][32];    // m0b or m1b columns of this block

  const int tid = threadIdx.x;
  const int b = tid & 31;
  const int u = tid >> 5;          // 0..15
  const int i0 = blockIdx.x * 2;
  const int kb = u * 32;
  const int grp = blockIdx.x >> 4;
  int baridx = 0;

  for (int t = 0; t < Tt; t++) {
    const size_t wo = (size_t)(t & (PR - 1)) * HB;
    const size_t ro = (size_t)((t + PR - 1) & (PR - 1)) * HB;
    const float* c0o = c0R + ro;
    const float* c1o = c1R + ro;
    const float* c2o = c2R + ro;

    // ---- p-phase: read p-partial accumulators of step t-1 (4KB), softmax weights ----
    {
      const int pslot = (t + Tt - 1) & (Tt - 1);   // t=0 -> slot 511 (zeros)
      if (tid < 64) {
        int which = tid >> 5, b2 = tid & 31;
        const float* pp = pacc + ((size_t)pslot * 2 + which) * 512;
        float s = mb3[which];
#pragma unroll
        for (int g = 0; g < 16; g++) s += pp[g * 32 + b2];
        s_ab[5 + which][b2] = sigf(s);
      }
      __syncthreads();
      if (tid < 32) {
        float p0 = s_ab[5][tid], p1 = s_ab[6][tid];
        float e0 = expf(1.f - p0), e1 = expf(p0 * (1.f - p1)), e2 = expf(p0 * p1);
        float inv = 1.f / (e0 + e1 + e2);
        s_ab[0][tid] = e0 * inv; s_ab[1][tid] = e1 * inv; s_ab[2][tid] = e2 * inv;
        float q0 = expf(1.f - p1), q1 = expf(p1);
        float qi = 1.f / (q0 + q1);
        s_ab[3][tid] = q0 * qi; s_ab[4][tid] = q1 * qi;
        if (t > 0 && blockIdx.x == 0) {
          out[((size_t)tid * Tt + (t - 1)) * 2 + 0] = p0;
          out[((size_t)tid * Tt + (t - 1)) * 2 + 1] = p1;
        }
      }
      __syncthreads();
    }

    const float a0 = s_ab[0][b], a1 = s_ab[1][b], a2 = s_ab[2][b];
    const float w10 = s_ab[3][b], w11 = s_ab[4][b];

    // ---- S1: gh0/gh1/gh2 with inline h-mixing; cell0 ----
    {
      float acc[18];
#pragma unroll
      for (int w = 0; w < 18; w++) acc[w] = 0.f;
      for (int kk = 0; kk < 32; kk += 4) {
        float mh0[4], mh1[4], vv2[4];
#pragma unroll
        for (int q = 0; q < 4; q++) {
          int k = kb + kk + q;
          float v0 = c0o[k * 32 + b], v1 = c1o[k * 32 + b], v2 = c2o[k * 32 + b];
          vv2[q] = v2;
          mh0[q] = a0 * v0 + a1 * v1 + a2 * v2;
          mh1[q] = w10 * v1 + w11 * v2;
        }
#pragma unroll
        for (int w = 0; w < 18; w++) {
          const int l = w / 6, rem = w % 6, g = rem >> 1, ii = rem & 1;
          const int row = g * 512 + i0 + ii;
          const float* wp = (l == 0) ? (Whh0 + (size_t)row * 512)
                                     : (Whh + ((size_t)(l - 1) * G3 + row) * 512);
          float4 w4 = *(const float4*)(wp + kb + kk);
          const float* mv = (l == 0) ? mh0 : (l == 1) ? mh1 : vv2;
          acc[w] += dot4f(w4, mv);
        }
      }
#pragma unroll
      for (int w = 0; w < 18; w++) red[u][w * 32 + b] = acc[w];
      __syncthreads();
      for (int o = tid; o < 18 * 32; o += NTHR) {
        float s = 0.f;
#pragma unroll
        for (int uu = 0; uu < 16; uu++) s += red[uu][o];
        int w = o >> 5, b2 = o & 31;
        int l = w / 6, rem = w % 6, g = rem >> 1, ii = rem & 1;
        int row = g * 512 + i0 + ii;
        if (l == 0) {
          s += bhh0[row];
          if (g < 2) s += GI0[((size_t)t * G3 + row) * 32 + b2];
          s_pre[rem][b2] = s;
        } else if (l == 1) {
          s_gh[rem][b2] = s + bhh[row];
        } else {
          s_gh[6 + rem][b2] = s + bhh[G3 + row];
        }
      }
      __syncthreads();
      if (tid < 64) {
        int ii = tid >> 5, bb = tid & 31;
        float r = sigf(s_pre[ii][bb]);
        float z = sigf(s_pre[2 + ii][bb]);
        float inn = GI0[((size_t)t * G3 + 1024 + i0 + ii) * 32 + bb];
        float n = tanhf(inn + r * s_pre[4 + ii][bb]);
        int idx = (i0 + ii) * 32 + bb;
        float v0 = c0o[idx], v1 = c1o[idx], v2 = c2o[idx];
        float h0old = s_ab[0][bb] * v0 + s_ab[1][bb] * v1 + s_ab[2][bb] * v2;
        dstore(&c0R[wo + idx], (1.f - z) * n + z * h0old);
      }
    }
    grid_barrier(bc1, bc2, gfl, baridx++);

    // ---- S2: gi1 (over cell0) + m0a; cell1 ----
    {
      const float* c0n = c0R + wo;
      float acc[8];
#pragma unroll
      for (int w = 0; w < 8; w++) acc[w] = 0.f;
      for (int kk = 0; kk < 32; kk += 4) {
        float v[4];
#pragma unroll
        for (int q = 0; q < 4; q++) v[q] = c0n[(kb + kk + q) * 32 + b];
#pragma unroll
        for (int w = 0; w < 8; w++) {
          const float* wp = (w < 6) ? (Wih + (size_t)((w >> 1) * 512 + i0 + (w & 1)) * 512)
                                    : (mW1 + (size_t)(i0 + (w - 6)) * 512);
          float4 w4 = *(const float4*)(wp + kb + kk);
          acc[w] += dot4f(w4, v);
        }
      }
#pragma unroll
      for (int w = 0; w < 8; w++) red[u][w * 32 + b] = acc[w];
      __syncthreads();
      for (int o = tid; o < 8 * 32; o += NTHR) {
        float s = 0.f;
#pragma unroll
        for (int uu = 0; uu < 16; uu++) s += red[uu][o];
        int w = o >> 5, b2 = o & 31;
        if (w < 6) {
          int row = (w >> 1) * 512 + i0 + (w & 1);
          s_gi[w][b2] = s + bih[row];
        } else {
          int col = i0 + (w - 6);
          dstore(&m0aR[wo + col * 32 + b2], fmaxf(s + mb1[col], 0.f));
        }
      }
      __syncthreads();
      if (tid < 64) {
        int ii = tid >> 5, bb = tid & 31;
        float r = sigf(s_gi[ii][bb] + s_gh[ii][bb]);
        float z = sigf(s_gi[2 + ii][bb] + s_gh[2 + ii][bb]);
        float n = tanhf(s_gi[4 + ii][bb] + r * s_gh[4 + ii][bb]);
        int idx = (i0 + ii) * 32 + bb;
        float h1old = s_ab[3][bb] * c1o[idx] + s_ab[4][bb] * c2o[idx];
        dstore(&c1R[wo + idx], (1.f - z) * n + z * h1old);
      }
    }
    grid_barrier(bc1, bc2, gfl, baridx++);

    // ---- S3: gi2 (over cell1) + m0b (over m0a) + m1a (over cell1); cell2; p0 partials ----
    {
      const float* c1n = c1R + wo;
      const float* m0a = m0aR + wo;
      float acc[10];
#pragma unroll
      for (int w = 0; w < 10; w++) acc[w] = 0.f;
      for (int kk = 0; kk < 32; kk += 4) {
        float v[4], vm[4];
#pragma unroll
        for (int q = 0; q < 4; q++) {
          v[q]  = c1n[(kb + kk + q) * 32 + b];
          vm[q] = m0a[(kb + kk + q) * 32 + b];
        }
#pragma unroll
        for (int w = 0; w < 10; w++) {
          const float* wp = (w < 6) ? (Wih + (size_t)(G3 + (w >> 1) * 512 + i0 + (w & 1)) * 512)
                          : (w < 8) ? (mW2 + (size_t)(i0 + (w - 6)) * 512)
                                    : (mW1 + (size_t)(512 + i0 + (w - 8)) * 512);
          float4 w4 = *(const float4*)(wp + kb + kk);
          acc[w] += dot4f(w4, (w < 6 || w >= 8) ? v : vm);
        }
      }
#pragma unroll
      for (int w = 0; w < 10; w++) red[u][w * 32 + b] = acc[w];
      __syncthreads();
      for (int o = tid; o < 10 * 32; o += NTHR) {
        float s = 0.f;
#pragma unroll
        for (int uu = 0; uu < 16; uu++) s += red[uu][o];
        int w = o >> 5, b2 = o & 31;
        if (w < 6) {
          int row = (w >> 1) * 512 + i0 + (w & 1);
          s_gi[w][b2] = s + bih[G3 + row];
        } else if (w < 8) {
          s_mb[w - 6][b2] = fmaxf(s + mb2[i0 + (w - 6)], 0.f);   // m0b cols
        } else {
          int col = i0 + (w - 8);
          dstore(&m1aR[wo + col * 32 + b2], fmaxf(s + mb1[512 + col], 0.f));
        }
      }
      __syncthreads();
      if (tid < 64) {
        int ii = tid >> 5, bb = tid & 31;
        float r = sigf(s_gi[ii][bb] + s_gh[6 + ii][bb]);
        float z = sigf(s_gi[2 + ii][bb] + s_gh[8 + ii][bb]);
        float n = tanhf(s_gi[4 + ii][bb] + r * s_gh[10 + ii][bb]);
        int idx = (i0 + ii) * 32 + bb;
        dstore(&c2R[wo + idx], (1.f - z) * n + z * c2o[idx]);
      } else if (tid < 96) {
        int b2 = tid - 64;
        float part = mW3[i0] * s_mb[0][b2] + mW3[i0 + 1] * s_mb[1][b2];
        __hip_atomic_fetch_add(&pacc[((size_t)t * 2 + 0) * 512 + grp * 32 + b2], part,
                               __ATOMIC_RELAXED, __HIP_MEMORY_SCOPE_AGENT);
      }
    }
    grid_barrier(bc1, bc2, gfl, baridx++);

    // ---- S4: m1b (over m1a, in-block) + p1 partials ----
    {
      const float* m1a = m1aR + wo;
      float acc2[2] = {0.f, 0.f};
      for (int kk = 0; kk < 32; kk += 4) {
        float vm[4];
#pragma unroll
        for (int q = 0; q < 4; q++) vm[q] = m1a[(kb + kk + q) * 32 + b];
#pragma unroll
        for (int w = 0; w < 2; w++) {
          const float* wp = mW2 + (size_t)(512 + i0 + w) * 512;
          float4 w4 = *(const float4*)(wp + kb + kk);
          acc2[w] += dot4f(w4, vm);
        }
      }
#pragma unroll
      for (int w = 0; w < 2; w++) red[u][w * 32 + b] = acc2[w];
      __syncthreads();
      if (tid < 64) {
        float s = 0.f;
#pragma unroll
        for (int uu = 0; uu < 16; uu++) s += red[uu][tid];
        int w = tid >> 5, b2 = tid & 31;
        s_mb[w][b2] = fmaxf(s + mb2[512 + i0 + w], 0.f);        // m1b cols
      }
      __syncthreads();
      if (tid >= 64 && tid < 96) {
        int b2 = tid - 64;
        float part = mW3[512 + i0] * s_mb[0][b2] + mW3[512 + i0 + 1] * s_mb[1][b2];
        __hip_atomic_fetch_add(&pacc[((size_t)t * 2 + 1) * 512 + grp * 32 + b2], part,
                               __ATOMIC_RELAXED, __HIP_MEMORY_SCOPE_AGENT);
      }
    }
    grid_barrier(bc1, bc2, gfl, baridx++);
  }

  // ---- final output column t = T-1 ----
  if (blockIdx.x == 0 && tid < 64) {
    int which = tid >> 5, b2 = tid & 31;
    const float* pp = pacc + ((size_t)(Tt - 1) * 2 + which) * 512;
    float s = mb3[which];
#pragma unroll
    for (int g = 0; g < 16; g++) s += pp[g * 32 + b2];
    out[((size_t)b2 * Tt + (Tt - 1)) * 2 + which] = sigf(s);
  }
}

extern "C" void kernel_launch(void* const* d_in, const int* in_sizes, int n_in,
                              void* d_out, int out_size, void* d_ws, size_t ws_size,
                              hipStream_t stream)
{
  (void)in_sizes; (void)n_in; (void)out_size;
  const float* x    = (const float*)d_in[0];
  const float* Wih0 = (const float*)d_in[1];
  const float* Whh0 = (const float*)d_in[2];
  const float* bih0 = (const float*)d_in[3];
  const float* bhh0 = (const float*)d_in[4];
  const float* Wih  = (const float*)d_in[5];
  const float* Whh  = (const float*)d_in[6];
  const float* bih  = (const float*)d_in[7];
  const float* bhh  = (const float*)d_in[8];
  const float* mW1  = (const float*)d_in[9];
  const float* mb1  = (const float*)d_in[10];
  const float* mW2  = (const float*)d_in[11];
  const float* mb2  = (const float*)d_in[12];
  const float* mW3  = (const float*)d_in[13];
  const float* mb3  = (const float*)d_in[14];
  float* out = (float*)d_out;

  char* ws = (char*)d_ws;
  size_t off = 0;
  auto take = [&](size_t bytes) { size_t o = off; off = (off + bytes + 255) & ~(size_t)255; return o; };
  unsigned* bc1 = (unsigned*)(ws + take((size_t)NBAR * 16 * 16 * 4));
  unsigned* bc2 = (unsigned*)(ws + take((size_t)NBAR * 16 * 4));
  unsigned* gfl = (unsigned*)(ws + take((size_t)16 * 16 * 4));
  float* c0R  = (float*)(ws + take((size_t)PR * HB * 4));
  float* c1R  = (float*)(ws + take((size_t)PR * HB * 4));
  float* c2R  = (float*)(ws + take((size_t)PR * HB * 4));
  float* m0aR = (float*)(ws + take((size_t)PR * HB * 4));
  float* m1aR = (float*)(ws + take((size_t)PR * HB * 4));
  float* pacc = (float*)(ws + take((size_t)Tt * 2 * 512 * 4));
  size_t zero_bytes = off;
  float* GI0 = (float*)(ws + take((size_t)Tt * G3 * Bb * 4));
  if (ws_size < off) return;  // fail visibly rather than corrupt

  hipMemsetAsync(d_ws, 0, zero_bytes, stream);
  gi0_gemm<<<dim3(Tt, G3 / 128), 256, 0, stream>>>(x, Wih0, bih0, GI0);
  hrnn_persist<<<NBLK, NTHR, 0, stream>>>(Whh0, bhh0, Wih, Whh, bih, bhh,
      mW1, mb1, mW2, mb2, mW3, mb3, GI0,
      c0R, c1R, c2R, m0aR, m1aR, pacc, bc1, bc2, gfl, out);
}